// Round 3
// baseline (995.351 us; speedup 1.0000x reference)
//
#include <hip/hip_runtime.h>
#include <cstdint>
#include <cstddef>

#define HID  1024
#define NEXP 16
#define TOPK 4
#define IMOE 512
#define ISH  1024
#define NTOK 8192

typedef __attribute__((ext_vector_type(8))) short bf16x8;
typedef __attribute__((ext_vector_type(4))) float f32x4;

__device__ inline unsigned short f2bf(float f) {
  unsigned int u = __float_as_uint(f);
  unsigned int r = (u + 0x7fffu + ((u >> 16) & 1u)) >> 16;
  return (unsigned short)r;
}

// ---------------- fp32 -> bf16 conversion (vectorized) ----------------
__global__ __launch_bounds__(256) void f2bf_kernel(const float* __restrict__ in,
                                                   unsigned short* __restrict__ out,
                                                   int n8) {
  int stride = gridDim.x * blockDim.x;
  for (int i = blockIdx.x * blockDim.x + threadIdx.x; i < n8; i += stride) {
    const float4* src = (const float4*)in + 2 * (size_t)i;
    float4 f0 = src[0], f1 = src[1];
    ushort4 a, b;
    a.x = f2bf(f0.x); a.y = f2bf(f0.y); a.z = f2bf(f0.z); a.w = f2bf(f0.w);
    b.x = f2bf(f1.x); b.y = f2bf(f1.y); b.z = f2bf(f1.z); b.w = f2bf(f1.w);
    ushort4* dst = (ushort4*)(out + 8 * (size_t)i);
    dst[0] = a; dst[1] = b;
  }
}

// ---------------- gating: one wave per token ----------------
__global__ __launch_bounds__(64) void gate_kernel(const float* __restrict__ x,
                                                  const float* __restrict__ gw,
                                                  const float* __restrict__ gb,
                                                  float* __restrict__ topk_w,
                                                  int* __restrict__ topk_i,
                                                  int* __restrict__ counts) {
  const int t = blockIdx.x;
  const int l = threadIdx.x;
  const float* xr = x + (size_t)t * HID;
  float part[NEXP];
#pragma unroll
  for (int e = 0; e < NEXP; ++e) part[e] = 0.f;
  for (int j = l; j < HID; j += 64) {
    float xv = xr[j];
#pragma unroll
    for (int e = 0; e < NEXP; ++e) part[e] += xv * gw[e * HID + j];
  }
#pragma unroll
  for (int e = 0; e < NEXP; ++e) {
#pragma unroll
    for (int off = 32; off >= 1; off >>= 1) part[e] += __shfl_xor(part[e], off, 64);
  }
  if (l == 0) {
    float sc[NEXP], sel[NEXP];
#pragma unroll
    for (int e = 0; e < NEXP; ++e) {
      sc[e] = 1.f / (1.f + expf(-part[e]));
      sel[e] = sc[e] + gb[e];
    }
    float tw[TOPK];
    int ti[TOPK];
    float s = 0.f;
#pragma unroll
    for (int k = 0; k < TOPK; ++k) {
      float best = -1e30f;
      int bi = 0;
#pragma unroll
      for (int e = 0; e < NEXP; ++e)
        if (sel[e] > best) { best = sel[e]; bi = e; }
      sel[bi] = -1e30f;
      ti[k] = bi;
      tw[k] = sc[bi];
      s += sc[bi];
    }
    float inv = 1.f / s;
#pragma unroll
    for (int k = 0; k < TOPK; ++k) {
      topk_w[t * TOPK + k] = tw[k] * inv;
      topk_i[t * TOPK + k] = ti[k];
      atomicAdd(&counts[ti[k]], 1);
    }
  }
}

__global__ void init_kernel(int* counts) {
  if (threadIdx.x < NEXP) counts[threadIdx.x] = 0;
}

__global__ void offs_kernel(const int* __restrict__ counts, int* __restrict__ offs,
                            int* __restrict__ fill) {
  if (threadIdx.x == 0) {
    int s = 0;
    for (int e = 0; e < NEXP; ++e) {
      offs[e] = s;
      s += counts[e];
      fill[e] = 0;
    }
  }
}

// ---------------- compaction: per-expert token lists ----------------
__global__ __launch_bounds__(256) void scatter_kernel(const int* __restrict__ topk_i,
                                                      const float* __restrict__ topk_w,
                                                      const int* __restrict__ offs,
                                                      int* __restrict__ fill,
                                                      int* __restrict__ list,
                                                      float* __restrict__ wlist) {
  __shared__ int lcnt[NEXP];
  __shared__ int lbase[NEXP];
  const int t = blockIdx.x * 256 + threadIdx.x;
  if (threadIdx.x < NEXP) lcnt[threadIdx.x] = 0;
  __syncthreads();
  int ei[TOPK], lp[TOPK];
  float ew[TOPK];
#pragma unroll
  for (int k = 0; k < TOPK; ++k) {
    ei[k] = topk_i[t * TOPK + k];
    ew[k] = topk_w[t * TOPK + k];
    lp[k] = atomicAdd(&lcnt[ei[k]], 1);
  }
  __syncthreads();
  if (threadIdx.x < NEXP) lbase[threadIdx.x] = atomicAdd(&fill[threadIdx.x], lcnt[threadIdx.x]);
  __syncthreads();
#pragma unroll
  for (int k = 0; k < TOPK; ++k) {
    int e = ei[k];
    int pidx = offs[e] + lbase[e] + lp[k];
    list[pidx] = t;
    wlist[pidx] = ew[k];
  }
}

// ---------------- MFMA GEMM (C = A @ B^T), m97-style ----------------
// MODE 0: plain fp32 write (shared down-proj)
// MODE 1: fused SwiGLU -> bf16 act (gate_up; BN=64, u rows at n, v rows at n+v_off)
// MODE 2: scatter epilogue: atomicAdd(out[list[row]] += wlist[row]*acc)
// GATHER: A rows indirected through list (routed gate_up)
template <int MODE, bool GATHER>
__global__ __launch_bounds__(256) void gemm_bt(const unsigned short* __restrict__ A,
                                               const unsigned short* __restrict__ Bfull,
                                               void* __restrict__ Cout,
                                               const int* __restrict__ list,
                                               const float* __restrict__ wlist,
                                               const int* __restrict__ counts,
                                               const int* __restrict__ offs,
                                               int K, int ldc, int Mfull, int v_off,
                                               long long strideB) {
  constexpr int BM = 128;
  constexpr int BN = (MODE == 1) ? 64 : 128;
  constexpr int NF = BN / 32;  // frags per wave in N (2 or 4)
  constexpr int BK = 32;

  const int e = blockIdx.z;
  const int n_e = counts ? counts[e] : Mfull;
  const int m0 = blockIdx.x * BM;
  if (m0 >= n_e) return;
  const int goff = offs ? offs[e] : 0;
  const int n0 = blockIdx.y * BN;
  const unsigned short* Bp = Bfull + (size_t)e * strideB;

  __shared__ __attribute__((aligned(16))) unsigned short As[BM * BK];
  __shared__ __attribute__((aligned(16))) unsigned short Bs[BN * BK];
  __shared__ __attribute__((aligned(16))) unsigned short Bs2[(MODE == 1) ? BN * BK : 8];

  const int tid = threadIdx.x;
  const int w = tid >> 6;
  const int l = tid & 63;
  const int wr = w >> 1;
  const int wc = w & 1;

  const f32x4 zero4 = {0.f, 0.f, 0.f, 0.f};
  f32x4 acc[4][NF];
  f32x4 accv[(MODE == 1) ? 4 : 1][(MODE == 1) ? NF : 1];
#pragma unroll
  for (int i = 0; i < 4; ++i)
#pragma unroll
    for (int j = 0; j < NF; ++j) {
      acc[i][j] = zero4;
      if (MODE == 1) accv[i][j] = zero4;
    }

  // staging geometry: lane covers 8 contiguous bf16 (16B); rows fixed across k-steps
  const int acol = (l & 3) * 8;
  int arow[BM / 64];
#pragma unroll
  for (int it = 0; it < BM / 64; ++it) {
    int r = (it * 2048 + w * 512 + l * 8) >> 5;
    int mi = m0 + r;
    int ar;
    if (MODE == 2)
      ar = goff + min(mi, n_e - 1);
    else if (GATHER)
      ar = list[goff + min(mi, n_e - 1)];
    else
      ar = mi;
    arow[it] = ar;
  }
  int brow[BN / 64];
#pragma unroll
  for (int it = 0; it < BN / 64; ++it) {
    int r = (it * 2048 + w * 512 + l * 8) >> 5;
    brow[it] = n0 + r;
  }

  for (int k0 = 0; k0 < K; k0 += BK) {
    __syncthreads();
#pragma unroll
    for (int it = 0; it < BM / 64; ++it) {
      const unsigned short* src = A + (size_t)arow[it] * K + (k0 + acol);
      __builtin_amdgcn_global_load_lds(
          (const __attribute__((address_space(1))) unsigned int*)src,
          (__attribute__((address_space(3))) unsigned int*)&As[it * 2048 + w * 512], 16, 0, 0);
    }
#pragma unroll
    for (int it = 0; it < BN / 64; ++it) {
      const unsigned short* src = Bp + (size_t)brow[it] * K + (k0 + acol);
      __builtin_amdgcn_global_load_lds(
          (const __attribute__((address_space(1))) unsigned int*)src,
          (__attribute__((address_space(3))) unsigned int*)&Bs[it * 2048 + w * 512], 16, 0, 0);
      if (MODE == 1) {
        const unsigned short* src2 = Bp + (size_t)(brow[it] + v_off) * K + (k0 + acol);
        __builtin_amdgcn_global_load_lds(
            (const __attribute__((address_space(1))) unsigned int*)src2,
            (__attribute__((address_space(3))) unsigned int*)&Bs2[it * 2048 + w * 512], 16, 0, 0);
      }
    }
    __syncthreads();

    const int lr = l & 15;
    const int k8 = (l >> 4) * 8;
    bf16x8 af[4];
#pragma unroll
    for (int i = 0; i < 4; ++i)
      af[i] = *(const bf16x8*)&As[(wr * 64 + i * 16 + lr) * BK + k8];
    bf16x8 bu[NF];
#pragma unroll
    for (int j = 0; j < NF; ++j)
      bu[j] = *(const bf16x8*)&Bs[(wc * (BN / 2) + j * 16 + lr) * BK + k8];
#pragma unroll
    for (int i = 0; i < 4; ++i)
#pragma unroll
      for (int j = 0; j < NF; ++j)
        acc[i][j] = __builtin_amdgcn_mfma_f32_16x16x32_bf16(af[i], bu[j], acc[i][j], 0, 0, 0);
    if (MODE == 1) {
      bf16x8 bv[NF];
#pragma unroll
      for (int j = 0; j < NF; ++j)
        bv[j] = *(const bf16x8*)&Bs2[(wc * (BN / 2) + j * 16 + lr) * BK + k8];
#pragma unroll
      for (int i = 0; i < 4; ++i)
#pragma unroll
        for (int j = 0; j < NF; ++j)
          accv[i][j] = __builtin_amdgcn_mfma_f32_16x16x32_bf16(af[i], bv[j], accv[i][j], 0, 0, 0);
    }
  }

  // epilogue; C/D layout: col = lane&15, row = (lane>>4)*4 + reg
  const int lr = l & 15;
  const int rbase = (l >> 4) * 4;
  if (MODE == 0) {
    float* C = (float*)Cout;
#pragma unroll
    for (int i = 0; i < 4; ++i)
#pragma unroll
      for (int r = 0; r < 4; ++r) {
        int row = m0 + wr * 64 + i * 16 + rbase + r;
#pragma unroll
        for (int j = 0; j < NF; ++j) {
          int col = n0 + wc * (BN / 2) + j * 16 + lr;
          C[(size_t)row * ldc + col] = acc[i][j][r];
        }
      }
  } else if (MODE == 1) {
    unsigned short* C = (unsigned short*)Cout;
#pragma unroll
    for (int i = 0; i < 4; ++i)
#pragma unroll
      for (int r = 0; r < 4; ++r) {
        int mi = m0 + wr * 64 + i * 16 + rbase + r;
        if (mi < n_e) {
#pragma unroll
          for (int j = 0; j < NF; ++j) {
            int col = n0 + wc * (BN / 2) + j * 16 + lr;
            float u = acc[i][j][r];
            float vv = accv[i][j][r];
            float sv = u / (1.f + __expf(-u));
            C[(size_t)(goff + mi) * ldc + col] = f2bf(sv * vv);
          }
        }
      }
  } else {
    float* C = (float*)Cout;
#pragma unroll
    for (int i = 0; i < 4; ++i)
#pragma unroll
      for (int r = 0; r < 4; ++r) {
        int mi = m0 + wr * 64 + i * 16 + rbase + r;
        if (mi < n_e) {
          int tk = list[goff + mi];
          float wgt = wlist[goff + mi];
#pragma unroll
          for (int j = 0; j < NF; ++j) {
            int col = n0 + wc * (BN / 2) + j * 16 + lr;
            atomicAdd(&C[(size_t)tk * ldc + col], wgt * acc[i][j][r]);
          }
        }
      }
  }
}

// ---------------- host launch ----------------
extern "C" void kernel_launch(void* const* d_in, const int* in_sizes, int n_in,
                              void* d_out, int out_size, void* d_ws, size_t ws_size,
                              hipStream_t stream) {
  const float* x = (const float*)d_in[0];
  const float* gw = (const float*)d_in[1];
  const float* gb = (const float*)d_in[2];
  const float* w13 = (const float*)d_in[3];
  const float* w2 = (const float*)d_in[4];
  const float* sw13 = (const float*)d_in[5];
  const float* sw2 = (const float*)d_in[6];
  float* out = (float*)d_out;

  char* p = (char*)d_ws;
  auto take = [&](size_t bytes) {
    char* r = p;
    p += (bytes + 255) & ~(size_t)255;
    return r;
  };
  unsigned short* x_bf = (unsigned short*)take((size_t)NTOK * HID * 2);
  unsigned short* w13_bf = (unsigned short*)take((size_t)NEXP * 2 * IMOE * HID * 2);
  unsigned short* w2_bf = (unsigned short*)take((size_t)NEXP * HID * IMOE * 2);
  unsigned short* sw13_bf = (unsigned short*)take((size_t)2 * ISH * HID * 2);
  unsigned short* sw2_bf = (unsigned short*)take((size_t)HID * ISH * 2);
  unsigned short* act_sh = (unsigned short*)take((size_t)NTOK * ISH * 2);
  unsigned short* act_rt = (unsigned short*)take((size_t)NTOK * TOPK * IMOE * 2);
  float* topk_w = (float*)take((size_t)NTOK * TOPK * 4);
  int* topk_i = (int*)take((size_t)NTOK * TOPK * 4);
  int* counts = (int*)take(256);
  int* offs = (int*)take(256);
  int* fill = (int*)take(256);
  int* list = (int*)take((size_t)NTOK * TOPK * 4);
  float* wlist = (float*)take((size_t)NTOK * TOPK * 4);

  auto conv = [&](const float* src, unsigned short* dst, size_t n) {
    int n8 = (int)(n / 8);
    int blocks = (n8 + 255) / 256;
    if (blocks > 4096) blocks = 4096;
    f2bf_kernel<<<dim3(blocks), dim3(256), 0, stream>>>(src, dst, n8);
  };
  conv(x, x_bf, (size_t)NTOK * HID);
  conv(w13, w13_bf, (size_t)NEXP * 2 * IMOE * HID);
  conv(w2, w2_bf, (size_t)NEXP * HID * IMOE);
  conv(sw13, sw13_bf, (size_t)2 * ISH * HID);
  conv(sw2, sw2_bf, (size_t)HID * ISH);

  init_kernel<<<1, 64, 0, stream>>>(counts);
  gate_kernel<<<NTOK, 64, 0, stream>>>(x, gw, gb, topk_w, topk_i, counts);
  offs_kernel<<<1, 64, 0, stream>>>(counts, offs, fill);
  scatter_kernel<<<NTOK / 256, 256, 0, stream>>>(topk_i, topk_w, offs, fill, list, wlist);

  // shared gate_up + SwiGLU: act_sh[T,ISH] = swiglu(x @ sw13^T)
  gemm_bt<1, false><<<dim3(NTOK / 128, ISH / 64, 1), 256, 0, stream>>>(
      x_bf, sw13_bf, act_sh, nullptr, nullptr, nullptr, nullptr, HID, ISH, NTOK, ISH, 0);
  // shared down: out[T,H] = act_sh @ sw2^T   (initializes d_out)
  gemm_bt<0, false><<<dim3(NTOK / 128, HID / 128, 1), 256, 0, stream>>>(
      act_sh, sw2_bf, out, nullptr, nullptr, nullptr, nullptr, ISH, HID, NTOK, 0, 0);
  // routed gate_up + SwiGLU over gathered tokens
  gemm_bt<1, true><<<dim3(NTOK / 128, IMOE / 64, NEXP), 256, 0, stream>>>(
      x_bf, w13_bf, act_rt, list, nullptr, counts, offs, HID, IMOE, 0, IMOE,
      (long long)2 * IMOE * HID);
  // routed down: out[token] += weight * (act_rt @ w2_e^T)
  gemm_bt<2, false><<<dim3(NTOK / 128, HID / 128, NEXP), 256, 0, stream>>>(
      act_rt, w2_bf, out, list, wlist, counts, offs, IMOE, HID, 0, 0,
      (long long)HID * IMOE);
}

// Round 13
// 903.409 us; speedup vs baseline: 1.1018x; 1.1018x over previous
//
#include <hip/hip_runtime.h>
#include <cstdint>
#include <cstddef>

#define HID  1024
#define NEXP 16
#define TOPK 4
#define IMOE 512
#define ISH  1024
#define NTOK 8192

typedef __attribute__((ext_vector_type(8))) short bf16x8;
typedef __attribute__((ext_vector_type(4))) float f32x4;

__device__ inline unsigned short f2bf(float f) {
  unsigned int u = __float_as_uint(f);
  unsigned int r = (u + 0x7fffu + ((u >> 16) & 1u)) >> 16;
  return (unsigned short)r;
}

// ---------------- fp32 -> bf16 conversion (vectorized) ----------------
__global__ __launch_bounds__(256) void f2bf_kernel(const float* __restrict__ in,
                                                   unsigned short* __restrict__ out,
                                                   int n8) {
  int stride = gridDim.x * blockDim.x;
  for (int i = blockIdx.x * blockDim.x + threadIdx.x; i < n8; i += stride) {
    const float4* src = (const float4*)in + 2 * (size_t)i;
    float4 f0 = src[0], f1 = src[1];
    ushort4 a, b;
    a.x = f2bf(f0.x); a.y = f2bf(f0.y); a.z = f2bf(f0.z); a.w = f2bf(f0.w);
    b.x = f2bf(f1.x); b.y = f2bf(f1.y); b.z = f2bf(f1.z); b.w = f2bf(f1.w);
    ushort4* dst = (ushort4*)(out + 8 * (size_t)i);
    dst[0] = a; dst[1] = b;
  }
}

// ---------------- gating: one wave per token (NO global atomics) ----------------
__global__ __launch_bounds__(64) void gate_kernel(const float* __restrict__ x,
                                                  const float* __restrict__ gw,
                                                  const float* __restrict__ gb,
                                                  float* __restrict__ topk_w,
                                                  int* __restrict__ topk_i) {
  const int t = blockIdx.x;
  const int l = threadIdx.x;
  const float* xr = x + (size_t)t * HID;
  float part[NEXP];
#pragma unroll
  for (int e = 0; e < NEXP; ++e) part[e] = 0.f;
  for (int j = l; j < HID; j += 64) {
    float xv = xr[j];
#pragma unroll
    for (int e = 0; e < NEXP; ++e) part[e] += xv * gw[e * HID + j];
  }
#pragma unroll
  for (int e = 0; e < NEXP; ++e) {
#pragma unroll
    for (int off = 32; off >= 1; off >>= 1) part[e] += __shfl_xor(part[e], off, 64);
  }
  if (l == 0) {
    float sc[NEXP], sel[NEXP];
#pragma unroll
    for (int e = 0; e < NEXP; ++e) {
      sc[e] = 1.f / (1.f + expf(-part[e]));
      sel[e] = sc[e] + gb[e];
    }
    float tw[TOPK];
    int ti[TOPK];
    float s = 0.f;
#pragma unroll
    for (int k = 0; k < TOPK; ++k) {
      float best = -1e30f;
      int bi = 0;
#pragma unroll
      for (int e = 0; e < NEXP; ++e)
        if (sel[e] > best) { best = sel[e]; bi = e; }
      sel[bi] = -1e30f;
      ti[k] = bi;
      tw[k] = sc[bi];
      s += sc[bi];
    }
    float inv = 1.f / s;
#pragma unroll
    for (int k = 0; k < TOPK; ++k) {
      topk_w[t * TOPK + k] = tw[k] * inv;
      topk_i[t * TOPK + k] = ti[k];
    }
  }
}

__global__ void init_kernel(int* counts) {
  if (threadIdx.x < NEXP) counts[threadIdx.x] = 0;
}

// ---------------- expert histogram: LDS-privatized (512 global atomics total) ----
__global__ __launch_bounds__(256) void count_kernel(const int* __restrict__ topk_i,
                                                    int* __restrict__ counts) {
  __shared__ int lcnt[NEXP];
  if (threadIdx.x < NEXP) lcnt[threadIdx.x] = 0;
  __syncthreads();
  const int t = blockIdx.x * 256 + threadIdx.x;
#pragma unroll
  for (int k = 0; k < TOPK; ++k) atomicAdd(&lcnt[topk_i[t * TOPK + k]], 1);
  __syncthreads();
  if (threadIdx.x < NEXP) atomicAdd(&counts[threadIdx.x], lcnt[threadIdx.x]);
}

__global__ void offs_kernel(const int* __restrict__ counts, int* __restrict__ offs,
                            int* __restrict__ fill) {
  if (threadIdx.x == 0) {
    int s = 0;
    for (int e = 0; e < NEXP; ++e) {
      offs[e] = s;
      s += counts[e];
      fill[e] = 0;
    }
  }
}

// ---------------- compaction: per-expert token lists ----------------
__global__ __launch_bounds__(256) void scatter_kernel(const int* __restrict__ topk_i,
                                                      const float* __restrict__ topk_w,
                                                      const int* __restrict__ offs,
                                                      int* __restrict__ fill,
                                                      int* __restrict__ list,
                                                      float* __restrict__ wlist) {
  __shared__ int lcnt[NEXP];
  __shared__ int lbase[NEXP];
  const int t = blockIdx.x * 256 + threadIdx.x;
  if (threadIdx.x < NEXP) lcnt[threadIdx.x] = 0;
  __syncthreads();
  int ei[TOPK], lp[TOPK];
  float ew[TOPK];
#pragma unroll
  for (int k = 0; k < TOPK; ++k) {
    ei[k] = topk_i[t * TOPK + k];
    ew[k] = topk_w[t * TOPK + k];
    lp[k] = atomicAdd(&lcnt[ei[k]], 1);
  }
  __syncthreads();
  if (threadIdx.x < NEXP) lbase[threadIdx.x] = atomicAdd(&fill[threadIdx.x], lcnt[threadIdx.x]);
  __syncthreads();
#pragma unroll
  for (int k = 0; k < TOPK; ++k) {
    int e = ei[k];
    int pidx = offs[e] + lbase[e] + lp[k];
    list[pidx] = t;
    wlist[pidx] = ew[k];
  }
}

// ---------------- MFMA GEMM (C = A @ B^T), m97-style ----------------
// MODE 0: plain fp32 write (shared down-proj)
// MODE 1: fused SwiGLU -> bf16 act (gate_up; BN=64, u rows at n, v rows at n+v_off)
// MODE 2: scatter epilogue: atomicAdd(out[list[row]] += wlist[row]*acc)
// GATHER: A rows indirected through list (routed gate_up)
template <int MODE, bool GATHER>
__global__ __launch_bounds__(256) void gemm_bt(const unsigned short* __restrict__ A,
                                               const unsigned short* __restrict__ Bfull,
                                               void* __restrict__ Cout,
                                               const int* __restrict__ list,
                                               const float* __restrict__ wlist,
                                               const int* __restrict__ counts,
                                               const int* __restrict__ offs,
                                               int K, int ldc, int Mfull, int v_off,
                                               long long strideB) {
  constexpr int BM = 128;
  constexpr int BN = (MODE == 1) ? 64 : 128;
  constexpr int NF = BN / 32;  // frags per wave in N (2 or 4)
  constexpr int BK = 32;

  const int e = blockIdx.z;
  const int n_e = counts ? counts[e] : Mfull;
  // XCD-aware swizzle of the M-tile index (T1). gridDim.x==64 for all call
  // sites, 64%8==0 -> (bx&7)*cpx + bx>>3 is bijective on [0,64). Groups 8
  // consecutive tiles per XCD so A-panel rows hit one L2 instead of eight.
  const int bx = ((int)blockIdx.x & 7) * ((int)gridDim.x >> 3) + ((int)blockIdx.x >> 3);
  const int m0 = bx * BM;
  if (m0 >= n_e) return;
  const int goff = offs ? offs[e] : 0;
  const int n0 = blockIdx.y * BN;
  const unsigned short* Bp = Bfull + (size_t)e * strideB;

  __shared__ __attribute__((aligned(16))) unsigned short As[BM * BK];
  __shared__ __attribute__((aligned(16))) unsigned short Bs[BN * BK];
  __shared__ __attribute__((aligned(16))) unsigned short Bs2[(MODE == 1) ? BN * BK : 8];

  const int tid = threadIdx.x;
  const int w = tid >> 6;
  const int l = tid & 63;
  const int wr = w >> 1;
  const int wc = w & 1;

  const f32x4 zero4 = {0.f, 0.f, 0.f, 0.f};
  f32x4 acc[4][NF];
  f32x4 accv[(MODE == 1) ? 4 : 1][(MODE == 1) ? NF : 1];
#pragma unroll
  for (int i = 0; i < 4; ++i)
#pragma unroll
    for (int j = 0; j < NF; ++j) {
      acc[i][j] = zero4;
      if (MODE == 1) accv[i][j] = zero4;
    }

  // staging geometry: lane covers 8 contiguous bf16 (16B); rows fixed across k-steps
  const int acol = (l & 3) * 8;
  int arow[BM / 64];
#pragma unroll
  for (int it = 0; it < BM / 64; ++it) {
    int r = (it * 2048 + w * 512 + l * 8) >> 5;
    int mi = m0 + r;
    int ar;
    if (MODE == 2)
      ar = goff + min(mi, n_e - 1);
    else if (GATHER)
      ar = list[goff + min(mi, n_e - 1)];
    else
      ar = mi;
    arow[it] = ar;
  }
  int brow[BN / 64];
#pragma unroll
  for (int it = 0; it < BN / 64; ++it) {
    int r = (it * 2048 + w * 512 + l * 8) >> 5;
    brow[it] = n0 + r;
  }

  for (int k0 = 0; k0 < K; k0 += BK) {
    __syncthreads();
#pragma unroll
    for (int it = 0; it < BM / 64; ++it) {
      const unsigned short* src = A + (size_t)arow[it] * K + (k0 + acol);
      __builtin_amdgcn_global_load_lds(
          (const __attribute__((address_space(1))) unsigned int*)src,
          (__attribute__((address_space(3))) unsigned int*)&As[it * 2048 + w * 512], 16, 0, 0);
    }
#pragma unroll
    for (int it = 0; it < BN / 64; ++it) {
      const unsigned short* src = Bp + (size_t)brow[it] * K + (k0 + acol);
      __builtin_amdgcn_global_load_lds(
          (const __attribute__((address_space(1))) unsigned int*)src,
          (__attribute__((address_space(3))) unsigned int*)&Bs[it * 2048 + w * 512], 16, 0, 0);
      if (MODE == 1) {
        const unsigned short* src2 = Bp + (size_t)(brow[it] + v_off) * K + (k0 + acol);
        __builtin_amdgcn_global_load_lds(
            (const __attribute__((address_space(1))) unsigned int*)src2,
            (__attribute__((address_space(3))) unsigned int*)&Bs2[it * 2048 + w * 512], 16, 0, 0);
      }
    }
    __syncthreads();

    const int lr = l & 15;
    const int k8 = (l >> 4) * 8;
    bf16x8 af[4];
#pragma unroll
    for (int i = 0; i < 4; ++i)
      af[i] = *(const bf16x8*)&As[(wr * 64 + i * 16 + lr) * BK + k8];
    bf16x8 bu[NF];
#pragma unroll
    for (int j = 0; j < NF; ++j)
      bu[j] = *(const bf16x8*)&Bs[(wc * (BN / 2) + j * 16 + lr) * BK + k8];
#pragma unroll
    for (int i = 0; i < 4; ++i)
#pragma unroll
      for (int j = 0; j < NF; ++j)
        acc[i][j] = __builtin_amdgcn_mfma_f32_16x16x32_bf16(af[i], bu[j], acc[i][j], 0, 0, 0);
    if (MODE == 1) {
      bf16x8 bv[NF];
#pragma unroll
      for (int j = 0; j < NF; ++j)
        bv[j] = *(const bf16x8*)&Bs2[(wc * (BN / 2) + j * 16 + lr) * BK + k8];
#pragma unroll
      for (int i = 0; i < 4; ++i)
#pragma unroll
        for (int j = 0; j < NF; ++j)
          accv[i][j] = __builtin_amdgcn_mfma_f32_16x16x32_bf16(af[i], bv[j], accv[i][j], 0, 0, 0);
    }
  }

  // epilogue; C/D layout: col = lane&15, row = (lane>>4)*4 + reg
  const int lr = l & 15;
  const int rbase = (l >> 4) * 4;
  if (MODE == 0) {
    float* C = (float*)Cout;
#pragma unroll
    for (int i = 0; i < 4; ++i)
#pragma unroll
      for (int r = 0; r < 4; ++r) {
        int row = m0 + wr * 64 + i * 16 + rbase + r;
#pragma unroll
        for (int j = 0; j < NF; ++j) {
          int col = n0 + wc * (BN / 2) + j * 16 + lr;
          C[(size_t)row * ldc + col] = acc[i][j][r];
        }
      }
  } else if (MODE == 1) {
    unsigned short* C = (unsigned short*)Cout;
#pragma unroll
    for (int i = 0; i < 4; ++i)
#pragma unroll
      for (int r = 0; r < 4; ++r) {
        int mi = m0 + wr * 64 + i * 16 + rbase + r;
        if (mi < n_e) {
#pragma unroll
          for (int j = 0; j < NF; ++j) {
            int col = n0 + wc * (BN / 2) + j * 16 + lr;
            float u = acc[i][j][r];
            float vv = accv[i][j][r];
            float sv = u / (1.f + __expf(-u));
            C[(size_t)(goff + mi) * ldc + col] = f2bf(sv * vv);
          }
        }
      }
  } else {
    float* C = (float*)Cout;
#pragma unroll
    for (int i = 0; i < 4; ++i)
#pragma unroll
      for (int r = 0; r < 4; ++r) {
        int mi = m0 + wr * 64 + i * 16 + rbase + r;
        if (mi < n_e) {
          int tk = list[goff + mi];
          float wgt = wlist[goff + mi];
#pragma unroll
          for (int j = 0; j < NF; ++j) {
            int col = n0 + wc * (BN / 2) + j * 16 + lr;
            atomicAdd(&C[(size_t)tk * ldc + col], wgt * acc[i][j][r]);
          }
        }
      }
  }
}

// ---------------- host launch ----------------
extern "C" void kernel_launch(void* const* d_in, const int* in_sizes, int n_in,
                              void* d_out, int out_size, void* d_ws, size_t ws_size,
                              hipStream_t stream) {
  const float* x = (const float*)d_in[0];
  const float* gw = (const float*)d_in[1];
  const float* gb = (const float*)d_in[2];
  const float* w13 = (const float*)d_in[3];
  const float* w2 = (const float*)d_in[4];
  const float* sw13 = (const float*)d_in[5];
  const float* sw2 = (const float*)d_in[6];
  float* out = (float*)d_out;

  char* p = (char*)d_ws;
  auto take = [&](size_t bytes) {
    char* r = p;
    p += (bytes + 255) & ~(size_t)255;
    return r;
  };
  unsigned short* x_bf = (unsigned short*)take((size_t)NTOK * HID * 2);
  unsigned short* w13_bf = (unsigned short*)take((size_t)NEXP * 2 * IMOE * HID * 2);
  unsigned short* w2_bf = (unsigned short*)take((size_t)NEXP * HID * IMOE * 2);
  unsigned short* sw13_bf = (unsigned short*)take((size_t)2 * ISH * HID * 2);
  unsigned short* sw2_bf = (unsigned short*)take((size_t)HID * ISH * 2);
  unsigned short* act_sh = (unsigned short*)take((size_t)NTOK * ISH * 2);
  unsigned short* act_rt = (unsigned short*)take((size_t)NTOK * TOPK * IMOE * 2);
  float* topk_w = (float*)take((size_t)NTOK * TOPK * 4);
  int* topk_i = (int*)take((size_t)NTOK * TOPK * 4);
  int* counts = (int*)take(256);
  int* offs = (int*)take(256);
  int* fill = (int*)take(256);
  int* list = (int*)take((size_t)NTOK * TOPK * 4);
  float* wlist = (float*)take((size_t)NTOK * TOPK * 4);

  auto conv = [&](const float* src, unsigned short* dst, size_t n) {
    int n8 = (int)(n / 8);
    int blocks = (n8 + 255) / 256;
    if (blocks > 4096) blocks = 4096;
    f2bf_kernel<<<dim3(blocks), dim3(256), 0, stream>>>(src, dst, n8);
  };
  conv(x, x_bf, (size_t)NTOK * HID);
  conv(w13, w13_bf, (size_t)NEXP * 2 * IMOE * HID);
  conv(w2, w2_bf, (size_t)NEXP * HID * IMOE);
  conv(sw13, sw13_bf, (size_t)2 * ISH * HID);
  conv(sw2, sw2_bf, (size_t)HID * ISH);

  init_kernel<<<1, 64, 0, stream>>>(counts);
  gate_kernel<<<NTOK, 64, 0, stream>>>(x, gw, gb, topk_w, topk_i);
  count_kernel<<<NTOK / 256, 256, 0, stream>>>(topk_i, counts);
  offs_kernel<<<1, 64, 0, stream>>>(counts, offs, fill);
  scatter_kernel<<<NTOK / 256, 256, 0, stream>>>(topk_i, topk_w, offs, fill, list, wlist);

  // shared gate_up + SwiGLU: act_sh[T,ISH] = swiglu(x @ sw13^T)
  gemm_bt<1, false><<<dim3(NTOK / 128, ISH / 64, 1), 256, 0, stream>>>(
      x_bf, sw13_bf, act_sh, nullptr, nullptr, nullptr, nullptr, HID, ISH, NTOK, ISH, 0);
  // shared down: out[T,H] = act_sh @ sw2^T   (initializes d_out)
  gemm_bt<0, false><<<dim3(NTOK / 128, HID / 128, 1), 256, 0, stream>>>(
      act_sh, sw2_bf, out, nullptr, nullptr, nullptr, nullptr, ISH, HID, NTOK, 0, 0);
  // routed gate_up + SwiGLU over gathered tokens
  gemm_bt<1, true><<<dim3(NTOK / 128, IMOE / 64, NEXP), 256, 0, stream>>>(
      x_bf, w13_bf, act_rt, list, nullptr, counts, offs, HID, IMOE, 0, IMOE,
      (long long)2 * IMOE * HID);
  // routed down: out[token] += weight * (act_rt @ w2_e^T)
  gemm_bt<2, false><<<dim3(NTOK / 128, HID / 128, NEXP), 256, 0, stream>>>(
      act_rt, w2_bf, out, list, wlist, counts, offs, IMOE, HID, 0, 0,
      (long long)HID * IMOE);
}